// Round 1
// baseline (354.457 us; speedup 1.0000x reference)
//
#include <hip/hip_runtime.h>
#include <hip/hip_bf16.h>

typedef __attribute__((ext_vector_type(8))) short short8;
typedef __attribute__((ext_vector_type(4))) float f32x4;
typedef unsigned short u16;

__device__ __forceinline__ u16 f2b(float f) {
  __hip_bfloat16 h = __float2bfloat16(f);
  union { __hip_bfloat16 h; u16 u; } cv; cv.h = h; return cv.u;
}

__device__ __forceinline__ f32x4 mfma16(short8 a, short8 b, f32x4 c) {
  return __builtin_amdgcn_mfma_f32_16x16x32_bf16(a, b, c, 0, 0, 0);
}

// ---- weight-norm prep: W[n][k] = v[n][k] * g[n]/||v_n||, bf16 out; rows >= Nreal zeroed ----
__global__ void wn_prep(const float* __restrict__ v, const float* __restrict__ g,
                        int K, int Nreal, u16* __restrict__ outW) {
  const int row = blockIdx.x;
  const int l = threadIdx.x;
  if (row >= Nreal) {
    for (int k = l; k < K; k += 64) outW[row * K + k] = 0;
    return;
  }
  const float* vr = v + (size_t)row * K;
  float ss = 0.f;
  for (int k = l * 4; k < K; k += 256) {
    f32x4 x = *(const f32x4*)(vr + k);
    ss += x.x * x.x + x.y * x.y + x.z * x.z + x.w * x.w;
  }
  #pragma unroll
  for (int m = 32; m >= 1; m >>= 1) ss += __shfl_xor(ss, m, 64);
  const float scale = g[row] / sqrtf(ss);
  for (int k = l; k < K; k += 64) outW[row * K + k] = f2b(vr[k] * scale);
}

// ---- bulk fp32 -> bf16 convert, 8 els/thread (n % 2048 == 0) ----
__global__ void cvt_bf16(const float* __restrict__ in, u16* __restrict__ out, int n) {
  const int i = (blockIdx.x * 256 + threadIdx.x) * 8;
  if (i >= n) return;
  f32x4 a = *(const f32x4*)(in + i);
  f32x4 b = *(const f32x4*)(in + i + 4);
  short8 r;
  r[0] = (short)f2b(a.x); r[1] = (short)f2b(a.y); r[2] = (short)f2b(a.z); r[3] = (short)f2b(a.w);
  r[4] = (short)f2b(b.x); r[5] = (short)f2b(b.y); r[6] = (short)f2b(b.z); r[7] = (short)f2b(b.w);
  *(short8*)(out + i) = r;
}

// ---- stage-1 GEMM: C = Xb @ Wb^T + bias. Block 64 rows x 128 cols, 4 waves (32x64 each).
// MODE 0: out0 = C (qp, fp32).  MODE 1: out0 = C (A2 = nf), out1 = C * qp[row/36] (A1). ----
template <int MODE>
__global__ __launch_bounds__(256) void gemm_s1(
    const u16* __restrict__ Xb, const u16* __restrict__ Wb,
    const float* __restrict__ bias, int K,
    float* __restrict__ out0, float* __restrict__ out1,
    const float* __restrict__ qp) {
  const int t = threadIdx.x, l = t & 63, w = t >> 6;
  const int lr = l & 15, lg = l >> 4;
  const int rh = w & 1, ch = w >> 1;
  const int bm = blockIdx.x * 64, bn = blockIdx.y * 128;

  const u16* xrow0 = Xb + (size_t)(bm + rh * 32 + lr) * K + lg * 8;
  const u16* xrow1 = xrow0 + (size_t)16 * K;
  const u16* wrow[4];
  #pragma unroll
  for (int nt = 0; nt < 4; nt++)
    wrow[nt] = Wb + (size_t)(bn + ch * 64 + nt * 16 + lr) * K + lg * 8;

  f32x4 acc[2][4] = {};
  for (int k = 0; k < K; k += 32) {
    short8 a0 = *(const short8*)(xrow0 + k);
    short8 a1 = *(const short8*)(xrow1 + k);
    #pragma unroll
    for (int nt = 0; nt < 4; nt++) {
      short8 bb = *(const short8*)(wrow[nt] + k);
      acc[0][nt] = mfma16(a0, bb, acc[0][nt]);
      acc[1][nt] = mfma16(a1, bb, acc[1][nt]);
    }
  }
  #pragma unroll
  for (int nt = 0; nt < 4; nt++) {
    const int c = bn + ch * 64 + nt * 16 + lr;
    const float bv = bias[c];
    #pragma unroll
    for (int rg = 0; rg < 2; rg++) {
      #pragma unroll
      for (int q = 0; q < 4; q++) {
        const int r = bm + rh * 32 + rg * 16 + lg * 4 + q;
        const float val = acc[rg][nt][q] + bv;
        out0[(size_t)r * 512 + c] = val;
        if (MODE == 1) out1[(size_t)r * 512 + c] = val * qp[(r / 36) * 512 + c];
      }
    }
  }
}

// ---- fused edge kernel: per 64-edge block.
// E[e][k] = A1[bi*36+i][k] * A2[bi*36+j][k]  (gen in LDS, bf16)
// h = relu(E @ W1^T + b1)  (MFMA, 4 waves: 32 edges x 128 cols each)
// out = h @ W2p^T + b2     (MFMA, W2 padded 8->16 rows) ----
__global__ __launch_bounds__(256) void edge_fused(
    const float* __restrict__ A1, const float* __restrict__ A2,
    const int* __restrict__ indexes,
    const u16* __restrict__ W1b, const float* __restrict__ b1,
    const u16* __restrict__ W2b, const float* __restrict__ b2,
    float* __restrict__ out) {
  __shared__ u16 lds[64 * 264];  // E phase: [64][72]; h phase: [64][264]
  const int t = threadIdx.x, l = t & 63, w = t >> 6;
  const int lr = l & 15, lg = l >> 4;
  const int rh = w & 1, ch = w >> 1;
  const int bm = blockIdx.x * 64;

  // gather pointers: thread handles edge (bm + l), k-quarter w of each 64-chunk
  const int idx = indexes[bm + l];
  const int bi = idx / 1296;
  const int rem = idx - bi * 1296;
  const int ii = rem / 36;
  const int jj = rem - ii * 36;
  const float* g1 = A1 + (size_t)(bi * 36 + ii) * 512 + w * 16;
  const float* g2 = A2 + (size_t)(bi * 36 + jj) * 512 + w * 16;
  u16* ew = &lds[l * 72 + w * 16];

  const u16* wbase[8];
  #pragma unroll
  for (int nt = 0; nt < 8; nt++)
    wbase[nt] = W1b + (size_t)(ch * 128 + nt * 16 + lr) * 512 + lg * 8;

  f32x4 acc[2][8] = {};

  for (int kc = 0; kc < 8; kc++) {
    __syncthreads();
    {
      float xv[16], yv[16];
      const float* p1 = g1 + kc * 64;
      const float* p2 = g2 + kc * 64;
      #pragma unroll
      for (int u = 0; u < 4; u++) {
        *(f32x4*)&xv[u * 4] = *(const f32x4*)(p1 + u * 4);
        *(f32x4*)&yv[u * 4] = *(const f32x4*)(p2 + u * 4);
      }
      short8 s0, s1;
      #pragma unroll
      for (int e = 0; e < 8; e++) {
        s0[e] = (short)f2b(xv[e] * yv[e]);
        s1[e] = (short)f2b(xv[e + 8] * yv[e + 8]);
      }
      *(short8*)ew = s0;
      *(short8*)(ew + 8) = s1;
    }
    __syncthreads();
    #pragma unroll
    for (int ks = 0; ks < 2; ks++) {
      short8 a0 = *(const short8*)&lds[(rh * 32 + lr) * 72 + ks * 32 + lg * 8];
      short8 a1 = *(const short8*)&lds[(rh * 32 + 16 + lr) * 72 + ks * 32 + lg * 8];
      const int ko = kc * 64 + ks * 32;
      #pragma unroll
      for (int nt = 0; nt < 8; nt++) {
        short8 bb = *(const short8*)(wbase[nt] + ko);
        acc[0][nt] = mfma16(a0, bb, acc[0][nt]);
        acc[1][nt] = mfma16(a1, bb, acc[1][nt]);
      }
    }
  }

  // epilogue 1: bias + relu -> bf16 h tile in LDS [64][264]
  __syncthreads();
  #pragma unroll
  for (int nt = 0; nt < 8; nt++) {
    const int c = ch * 128 + nt * 16 + lr;
    const float bv = b1[c];
    #pragma unroll
    for (int rg = 0; rg < 2; rg++) {
      #pragma unroll
      for (int q = 0; q < 4; q++) {
        const int r = rh * 32 + rg * 16 + lg * 4 + q;
        lds[r * 264 + c] = f2b(fmaxf(acc[rg][nt][q] + bv, 0.f));
      }
    }
  }
  __syncthreads();

  // GEMM2: wave w -> edges [bm + w*16, +16), K=256, N=16 (8 real)
  f32x4 acc2 = {0.f, 0.f, 0.f, 0.f};
  #pragma unroll
  for (int kk = 0; kk < 8; kk++) {
    short8 a = *(const short8*)&lds[(w * 16 + lr) * 264 + kk * 32 + lg * 8];
    short8 bb = *(const short8*)(W2b + (size_t)lr * 256 + kk * 32 + lg * 8);
    acc2 = mfma16(a, bb, acc2);
  }
  if (lr < 8) {
    const float bv2 = b2[lr];
    #pragma unroll
    for (int q = 0; q < 4; q++) {
      const int e = bm + w * 16 + lg * 4 + q;
      out[(size_t)e * 8 + lr] = acc2[q] + bv2;
    }
  }
}

extern "C" void kernel_launch(void* const* d_in, const int* in_sizes, int n_in,
                              void* d_out, int out_size, void* d_ws, size_t ws_size,
                              hipStream_t stream) {
  const float* node_feats = (const float*)d_in[0];   // [128][36][2048]
  const float* q_feats    = (const float*)d_in[1];   // [128][1024]
  const int*   indexes    = (const int*)d_in[2];     // [161280]
  const float* v_obj = (const float*)d_in[3];
  const float* g_obj = (const float*)d_in[4];
  const float* b_obj = (const float*)d_in[5];
  const float* v_q   = (const float*)d_in[6];
  const float* g_q   = (const float*)d_in[7];
  const float* b_q   = (const float*)d_in[8];
  const float* v_l1  = (const float*)d_in[9];
  const float* g_l1  = (const float*)d_in[10];
  const float* b_l1  = (const float*)d_in[11];
  const float* v_l2  = (const float*)d_in[12];
  const float* g_l2  = (const float*)d_in[13];
  const float* b_l2  = (const float*)d_in[14];
  float* out = (float*)d_out;

  char* ws = (char*)d_ws;
  u16*   node_b = (u16*)(ws + 0);               // 4608*2048*2 = 18,874,368
  u16*   q_b    = (u16*)(ws + 18874368);        // 128*1024*2  =    262,144
  u16*   Wobjb  = (u16*)(ws + 19136512);        // 512*2048*2  =  2,097,152
  u16*   Wqb    = (u16*)(ws + 21233664);        // 512*1024*2  =  1,048,576
  u16*   Wl1b   = (u16*)(ws + 22282240);        // 256*512*2   =    262,144
  u16*   Wl2b   = (u16*)(ws + 22544384);        // 16*256*2    =      8,192
  float* qp     = (float*)(ws + 22552576);      // 128*512*4   =    262,144
  float* A1     = (float*)(ws + 22814720);      // 4608*512*4  =  9,437,184
  float* A2     = (float*)(ws + 32251904);      // 4608*512*4  =  9,437,184  (end ~41.7 MB)

  wn_prep<<<dim3(512), dim3(64), 0, stream>>>(v_obj, g_obj, 2048, 512, Wobjb);
  wn_prep<<<dim3(512), dim3(64), 0, stream>>>(v_q,   g_q,   1024, 512, Wqb);
  wn_prep<<<dim3(256), dim3(64), 0, stream>>>(v_l1,  g_l1,  512,  256, Wl1b);
  wn_prep<<<dim3(16),  dim3(64), 0, stream>>>(v_l2,  g_l2,  256,  8,   Wl2b);

  cvt_bf16<<<dim3(9437184 / 2048), dim3(256), 0, stream>>>(node_feats, node_b, 9437184);
  cvt_bf16<<<dim3(131072 / 2048),  dim3(256), 0, stream>>>(q_feats,    q_b,    131072);

  gemm_s1<0><<<dim3(2, 4),  dim3(256), 0, stream>>>(q_b,    Wqb,   b_q,   1024, qp, (float*)nullptr, (const float*)nullptr);
  gemm_s1<1><<<dim3(72, 4), dim3(256), 0, stream>>>(node_b, Wobjb, b_obj, 2048, A2, A1, qp);

  edge_fused<<<dim3(2520), dim3(256), 0, stream>>>(A1, A2, indexes, Wl1b, b_l1, Wl2b, b_l2, out);
}

// Round 2
// 232.420 us; speedup vs baseline: 1.5251x; 1.5251x over previous
//
#include <hip/hip_runtime.h>
#include <hip/hip_bf16.h>

typedef __attribute__((ext_vector_type(8))) short short8;
typedef __attribute__((ext_vector_type(4))) float f32x4;
typedef unsigned short u16;
typedef unsigned int u32;

__device__ __forceinline__ u16 f2b(float f) {
  __hip_bfloat16 h = __float2bfloat16(f);
  union { __hip_bfloat16 h; u16 u; } cv; cv.h = h; return cv.u;
}

__device__ __forceinline__ f32x4 mfma16(short8 a, short8 b, f32x4 c) {
  return __builtin_amdgcn_mfma_f32_16x16x32_bf16(a, b, c, 0, 0, 0);
}

// bf16-pair elementwise product: (a.lo*b.lo, a.hi*b.hi) -> packed bf16 pair
__device__ __forceinline__ u32 bmul2(u32 a, u32 b) {
  float al = __uint_as_float(a << 16);
  float ah = __uint_as_float(a & 0xffff0000u);
  float bl = __uint_as_float(b << 16);
  float bh = __uint_as_float(b & 0xffff0000u);
  return (u32)f2b(al * bl) | ((u32)f2b(ah * bh) << 16);
}

// build short8 from two 8B LDS reads (8-byte aligned addresses)
__device__ __forceinline__ short8 ld_frag8(const char* p) {
  uint2 a = *(const uint2*)(p);
  uint2 b = *(const uint2*)(p + 8);
  union { short8 s; u32 u[4]; } r;
  r.u[0] = a.x; r.u[1] = a.y; r.u[2] = b.x; r.u[3] = b.y;
  return r.s;
}

__device__ __forceinline__ short8 ld_frag16(const char* p) {
  union { short8 s; int4 v; } r;
  r.v = *(const int4*)(p);
  return r.s;
}

// ---- weight-norm prep: W[n][k] = v[n][k] * g[n]/||v_n||, bf16 out; rows >= Nreal zeroed ----
__global__ void wn_prep(const float* __restrict__ v, const float* __restrict__ g,
                        int K, int Nreal, u16* __restrict__ outW) {
  const int row = blockIdx.x;
  const int l = threadIdx.x;
  if (row >= Nreal) {
    for (int k = l; k < K; k += 64) outW[row * K + k] = 0;
    return;
  }
  const float* vr = v + (size_t)row * K;
  float ss = 0.f;
  for (int k = l * 4; k < K; k += 256) {
    f32x4 x = *(const f32x4*)(vr + k);
    ss += x.x * x.x + x.y * x.y + x.z * x.z + x.w * x.w;
  }
  #pragma unroll
  for (int m = 32; m >= 1; m >>= 1) ss += __shfl_xor(ss, m, 64);
  const float scale = g[row] / sqrtf(ss);
  for (int k = l; k < K; k += 64) outW[row * K + k] = f2b(vr[k] * scale);
}

// ---- W1 prep in chunk-fragment layout: W1f[kc(16)][row(256)][36] (els 32..35 = 0 pad) ----
__global__ void wn_prep_l1(const float* __restrict__ v, const float* __restrict__ g,
                           u16* __restrict__ W1f) {
  const int row = blockIdx.x;   // 256
  const int l = threadIdx.x;    // 64
  const float* vr = v + (size_t)row * 512;
  float ss = 0.f;
  for (int k = l * 4; k < 512; k += 256) {
    f32x4 x = *(const f32x4*)(vr + k);
    ss += x.x * x.x + x.y * x.y + x.z * x.z + x.w * x.w;
  }
  #pragma unroll
  for (int m = 32; m >= 1; m >>= 1) ss += __shfl_xor(ss, m, 64);
  const float scale = g[row] / sqrtf(ss);
  for (int c = l; c < 16 * 36; c += 64) {
    int kc = c / 36, el = c - kc * 36;
    u16 val = (el < 32) ? f2b(vr[kc * 32 + el] * scale) : (u16)0;
    W1f[kc * 9216 + row * 36 + el] = val;
  }
}

// ---- bulk fp32 -> bf16 convert, 8 els/thread (n % 2048 == 0) ----
__global__ void cvt_bf16(const float* __restrict__ in, u16* __restrict__ out, int n) {
  const int i = (blockIdx.x * 256 + threadIdx.x) * 8;
  if (i >= n) return;
  f32x4 a = *(const f32x4*)(in + i);
  f32x4 b = *(const f32x4*)(in + i + 4);
  short8 r;
  r[0] = (short)f2b(a.x); r[1] = (short)f2b(a.y); r[2] = (short)f2b(a.z); r[3] = (short)f2b(a.w);
  r[4] = (short)f2b(b.x); r[5] = (short)f2b(b.y); r[6] = (short)f2b(b.z); r[7] = (short)f2b(b.w);
  *(short8*)(out + i) = r;
}

// ---- pos map: init to -1, then scatter pos[bi*1312 + i*36 + j] = m ----
__global__ void pos_init(int* __restrict__ pos, int n) {
  int t = blockIdx.x * 256 + threadIdx.x;
  if (t < n) pos[t] = -1;
}
__global__ void pos_scatter(const int* __restrict__ indexes, int* __restrict__ pos, int n) {
  int m = blockIdx.x * 256 + threadIdx.x;
  if (m >= n) return;
  int idx = indexes[m];
  int bi = idx / 1296;
  int rem = idx - bi * 1296;
  pos[bi * 1312 + rem] = m;   // rem = i*36 + j
}

// ---- stage-1 GEMM (register-direct, kept from R1). MODE 0: fp32 qp out.
// MODE 1: bf16 A2=nf, bf16 A1=nf*qp. ----
template <int MODE>
__global__ __launch_bounds__(256) void gemm_s1(
    const u16* __restrict__ Xb, const u16* __restrict__ Wb,
    const float* __restrict__ bias, int K,
    float* __restrict__ fout, u16* __restrict__ o_a2, u16* __restrict__ o_a1,
    const float* __restrict__ qp) {
  const int t = threadIdx.x, l = t & 63, w = t >> 6;
  const int lr = l & 15, lg = l >> 4;
  const int rh = w & 1, ch = w >> 1;
  const int bm = blockIdx.x * 64, bn = blockIdx.y * 128;

  const u16* xrow0 = Xb + (size_t)(bm + rh * 32 + lr) * K + lg * 8;
  const u16* xrow1 = xrow0 + (size_t)16 * K;
  const u16* wrow[4];
  #pragma unroll
  for (int nt = 0; nt < 4; nt++)
    wrow[nt] = Wb + (size_t)(bn + ch * 64 + nt * 16 + lr) * K + lg * 8;

  f32x4 acc[2][4] = {};
  for (int k = 0; k < K; k += 32) {
    short8 a0 = *(const short8*)(xrow0 + k);
    short8 a1 = *(const short8*)(xrow1 + k);
    #pragma unroll
    for (int nt = 0; nt < 4; nt++) {
      short8 bb = *(const short8*)(wrow[nt] + k);
      acc[0][nt] = mfma16(a0, bb, acc[0][nt]);
      acc[1][nt] = mfma16(a1, bb, acc[1][nt]);
    }
  }
  #pragma unroll
  for (int nt = 0; nt < 4; nt++) {
    const int c = bn + ch * 64 + nt * 16 + lr;
    const float bv = bias[c];
    #pragma unroll
    for (int rg = 0; rg < 2; rg++) {
      #pragma unroll
      for (int q = 0; q < 4; q++) {
        const int r = bm + rh * 32 + rg * 16 + lg * 4 + q;
        const float val = acc[rg][nt][q] + bv;
        if (MODE == 0) {
          fout[(size_t)r * 512 + c] = val;
        } else {
          o_a2[(size_t)r * 512 + c] = f2b(val);
          o_a1[(size_t)r * 512 + c] = f2b(val * qp[(r / 36) * 512 + c]);
        }
      }
    }
  }
}

// ================= fused edge kernel v2 =================
// Per block: one batch bi, M-rows [mb, mb+MT*16) of the 1296-row (i*36+j) grid.
// E[row][k] = A1[bi,i] * A2[bi,j], generated from LDS-resident A1/A2 slices.
// GEMM1: h = relu(E @ W1^T + b1)  (K=512 in 16 chunks of 32, Ec/W1c double-buffered)
// GEMM2: out = h @ W2p^T + b2, scattered to out rows via pos map.
#define OFF_A1 0
#define OFF_A2 37440
#define OFF_EC 74880          // 2 x [256][44] u16 = 2 x 22528
#define OFF_W1 119936         // 2 x [256][36] u16 = 2 x 18432
#define SMEM_BYTES 156800

template <int MT>   // Mtiles per block: 16 (full, 256 rows) or 2 (tail incl. pad)
__global__ __launch_bounds__(512, 2) void edge_v2(
    const u16* __restrict__ A1g, const u16* __restrict__ A2g,
    const u16* __restrict__ W1f, const float* __restrict__ b1,
    const u16* __restrict__ W2p, const float* __restrict__ b2,
    const int* __restrict__ pos, float* __restrict__ out) {
  extern __shared__ char smem[];
  const int t = threadIdx.x, l = t & 63, w = t >> 6;
  const int lr = l & 15, lg = l >> 4;
  const int wm = w >> 2, wn = w & 3;     // 2 M-waves x 4 N-waves
  const int MT_W = MT / 2;

  const int bi = blockIdx.y;
  const int mb = (MT == 16) ? blockIdx.x * 256 : 1280;

  // ---- stage A1/A2 batch slices (36 rows x 512 bf16 each) into padded LDS [36][520] ----
  #pragma unroll
  for (int it = 0; it < 9; it++) {
    int c = t + it * 512;          // 4608 16B-chunks total
    int rr = c >> 6, off = c & 63;
    const u16* src = (rr < 36) ? (A1g + (size_t)(bi * 36 + rr) * 512 + off * 8)
                               : (A2g + (size_t)(bi * 36 + rr - 36) * 512 + off * 8);
    char* dst = smem + ((rr < 36) ? (OFF_A1 + rr * 1040) : (OFF_A2 + (rr - 36) * 1040)) + off * 16;
    *(int4*)dst = *(const int4*)src;
  }
  // ---- stage W1 chunk kc=0 into buffer 0 (linear copy, 1152 16B chunks) ----
  #pragma unroll
  for (int it = 0; it < 3; it++) {
    int c = t + it * 512;
    if (c < 1152) *(int4*)(smem + OFF_W1 + c * 16) = *(const int4*)(W1f + c * 8);
  }
  __syncthreads();

  // ---- E-gen setup: thread -> (row = t>>1, 16-el half = t&1) ----
  const int erow = t >> 1;
  const int brow = mb + erow;
  const int ii = brow / 36;
  const int jj = brow - ii * 36;
  const char* a1base = smem + OFF_A1 + ii * 1040 + (t & 1) * 32;  // ii==36 (pad) spills into A2 region: safe
  const char* a2base = smem + OFF_A2 + jj * 1040 + (t & 1) * 32;
  char* ecbase = smem + OFF_EC + erow * 88 + (t & 1) * 32;
  const bool egen_on = (erow < MT * 16);

  // E-gen for kc=0 into Ec buffer 0
  if (egen_on) {
    int4 x0 = *(const int4*)(a1base);
    int4 x1 = *(const int4*)(a1base + 16);
    int4 y0 = *(const int4*)(a2base);
    int4 y1 = *(const int4*)(a2base + 16);
    u32 e0 = bmul2(x0.x, y0.x), e1 = bmul2(x0.y, y0.y), e2 = bmul2(x0.z, y0.z), e3 = bmul2(x0.w, y0.w);
    u32 e4 = bmul2(x1.x, y1.x), e5 = bmul2(x1.y, y1.y), e6 = bmul2(x1.z, y1.z), e7 = bmul2(x1.w, y1.w);
    *(uint2*)(ecbase)      = make_uint2(e0, e1);
    *(uint2*)(ecbase + 8)  = make_uint2(e2, e3);
    *(uint2*)(ecbase + 16) = make_uint2(e4, e5);
    *(uint2*)(ecbase + 24) = make_uint2(e6, e7);
  }
  __syncthreads();

  float b1v[4];
  #pragma unroll
  for (int n = 0; n < 4; n++) b1v[n] = b1[wn * 64 + n * 16 + lr];

  f32x4 acc[MT_W > 0 ? MT_W : 1][4] = {};

  // ---- main K loop: 16 chunks of 32 ----
  for (int kc = 0; kc < 16; kc++) {
    const int cur = kc & 1, nxt = cur ^ 1;
    const bool more = (kc < 15);

    // issue W1 stage loads for kc+1 (global -> regs)
    int4 sreg0, sreg1, sreg2;
    if (more) {
      const u16* wsrc = W1f + (size_t)(kc + 1) * 9216;
      sreg0 = *(const int4*)(wsrc + (t) * 8);
      sreg1 = *(const int4*)(wsrc + (t + 512) * 8);
      if (t < 128) sreg2 = *(const int4*)(wsrc + (t + 1024) * 8);
    }
    // E-gen for kc+1 into Ec[nxt]
    if (more && egen_on) {
      const char* p1 = a1base + (kc + 1) * 64;
      const char* p2 = a2base + (kc + 1) * 64;
      int4 x0 = *(const int4*)(p1);
      int4 x1 = *(const int4*)(p1 + 16);
      int4 y0 = *(const int4*)(p2);
      int4 y1 = *(const int4*)(p2 + 16);
      u32 e0 = bmul2(x0.x, y0.x), e1 = bmul2(x0.y, y0.y), e2 = bmul2(x0.z, y0.z), e3 = bmul2(x0.w, y0.w);
      u32 e4 = bmul2(x1.x, y1.x), e5 = bmul2(x1.y, y1.y), e6 = bmul2(x1.z, y1.z), e7 = bmul2(x1.w, y1.w);
      char* eo = ecbase + nxt * 22528;
      *(uint2*)(eo)      = make_uint2(e0, e1);
      *(uint2*)(eo + 8)  = make_uint2(e2, e3);
      *(uint2*)(eo + 16) = make_uint2(e4, e5);
      *(uint2*)(eo + 24) = make_uint2(e6, e7);
    }
    // MFMA for kc from Ec[cur], W1c[cur]
    {
      const char* ecr = smem + OFF_EC + cur * 22528;
      const char* w1r = smem + OFF_W1 + cur * 18432;
      short8 bfr[4];
      #pragma unroll
      for (int n = 0; n < 4; n++)
        bfr[n] = ld_frag8(w1r + (wn * 64 + n * 16 + lr) * 72 + lg * 16);
      #pragma unroll
      for (int m = 0; m < MT_W; m++) {
        short8 af = ld_frag8(ecr + ((wm * MT_W + m) * 16 + lr) * 88 + lg * 16);
        #pragma unroll
        for (int n = 0; n < 4; n++)
          acc[m][n] = mfma16(af, bfr[n], acc[m][n]);
      }
    }
    // write staged W1 regs -> W1c[nxt]
    if (more) {
      char* wdst = smem + OFF_W1 + nxt * 18432;
      *(int4*)(wdst + t * 16) = sreg0;
      *(int4*)(wdst + (t + 512) * 16) = sreg1;
      if (t < 128) *(int4*)(wdst + (t + 1024) * 16) = sreg2;
    }
    __syncthreads();
  }

  // ---- epilogue 1: bias+relu -> bf16 h tile in LDS [256][264] (aliases A1/A2/Ec) ----
  #pragma unroll
  for (int m = 0; m < MT_W; m++) {
    #pragma unroll
    for (int n = 0; n < 4; n++) {
      const int c = wn * 64 + n * 16 + lr;
      #pragma unroll
      for (int q = 0; q < 4; q++) {
        const int r = (wm * MT_W + m) * 16 + lg * 4 + q;
        *(u16*)(smem + r * 528 + c * 2) = f2b(fmaxf(acc[m][n][q] + b1v[n], 0.f));
      }
    }
  }
  __syncthreads();

  // ---- GEMM2: out = h @ W2p^T + b2, K=256 ----
  short8 bfr2[8];
  #pragma unroll
  for (int kk = 0; kk < 8; kk++)
    bfr2[kk] = ld_frag16((const char*)(W2p + lr * 256 + kk * 32 + lg * 8));

  const int T2 = (MT + 7) / 8;    // tiles per wave
  #pragma unroll
  for (int tt = 0; tt < T2; tt++) {
    const int tile = w * T2 + tt;
    if (tile < MT) {
      f32x4 a2c = {0.f, 0.f, 0.f, 0.f};
      #pragma unroll
      for (int kk = 0; kk < 8; kk++) {
        short8 af = ld_frag16(smem + (tile * 16 + lr) * 528 + kk * 64 + lg * 16);
        a2c = mfma16(af, bfr2[kk], a2c);
      }
      if (lr < 8) {
        const float b2v = b2[lr];
        #pragma unroll
        for (int q = 0; q < 4; q++) {
          const int rl = tile * 16 + lg * 4 + q;
          const int m = pos[bi * 1312 + mb + rl];
          if (m >= 0) out[(size_t)m * 8 + lr] = a2c[q] + b2v;
        }
      }
    }
  }
}

extern "C" void kernel_launch(void* const* d_in, const int* in_sizes, int n_in,
                              void* d_out, int out_size, void* d_ws, size_t ws_size,
                              hipStream_t stream) {
  const float* node_feats = (const float*)d_in[0];   // [128][36][2048]
  const float* q_feats    = (const float*)d_in[1];   // [128][1024]
  const int*   indexes    = (const int*)d_in[2];     // [161280]
  const float* v_obj = (const float*)d_in[3];
  const float* g_obj = (const float*)d_in[4];
  const float* b_obj = (const float*)d_in[5];
  const float* v_q   = (const float*)d_in[6];
  const float* g_q   = (const float*)d_in[7];
  const float* b_q   = (const float*)d_in[8];
  const float* v_l1  = (const float*)d_in[9];
  const float* g_l1  = (const float*)d_in[10];
  const float* b_l1  = (const float*)d_in[11];
  const float* v_l2  = (const float*)d_in[12];
  const float* g_l2  = (const float*)d_in[13];
  const float* b_l2  = (const float*)d_in[14];
  float* out = (float*)d_out;

  char* ws = (char*)d_ws;
  u16*   node_b = (u16*)(ws + 0);               // 18,874,368
  u16*   q_b    = (u16*)(ws + 18874368);        //    262,144
  u16*   Wobjb  = (u16*)(ws + 19136512);        //  2,097,152
  u16*   Wqb    = (u16*)(ws + 21233664);        //  1,048,576
  u16*   W1f    = (u16*)(ws + 22282240);        //    294,912 (16x256x36)
  u16*   W2p    = (u16*)(ws + 22577152);        //      8,192 (16x256)
  float* qp     = (float*)(ws + 22585344);      //    262,144
  u16*   A1b    = (u16*)(ws + 22847488);        //  4,718,592 (4608x512 bf16, nf*qp)
  u16*   A2b    = (u16*)(ws + 27566080);        //  4,718,592 (nf)
  int*   pos    = (int*)(ws + 32284672);        //    671,744 (128x1312)

  wn_prep<<<dim3(512), dim3(64), 0, stream>>>(v_obj, g_obj, 2048, 512, Wobjb);
  wn_prep<<<dim3(512), dim3(64), 0, stream>>>(v_q,   g_q,   1024, 512, Wqb);
  wn_prep_l1<<<dim3(256), dim3(64), 0, stream>>>(v_l1, g_l1, W1f);
  wn_prep<<<dim3(16),  dim3(64), 0, stream>>>(v_l2,  g_l2,  256,  8,   W2p);

  cvt_bf16<<<dim3(4608), dim3(256), 0, stream>>>(node_feats, node_b, 9437184);
  cvt_bf16<<<dim3(64),   dim3(256), 0, stream>>>(q_feats,    q_b,    131072);

  pos_init<<<dim3(656), dim3(256), 0, stream>>>(pos, 128 * 1312);
  pos_scatter<<<dim3(630), dim3(256), 0, stream>>>(indexes, pos, 161280);

  gemm_s1<0><<<dim3(2, 4),  dim3(256), 0, stream>>>(q_b, Wqb, b_q, 1024, qp, nullptr, nullptr, nullptr);
  gemm_s1<1><<<dim3(72, 4), dim3(256), 0, stream>>>(node_b, Wobjb, b_obj, 2048, nullptr, A2b, A1b, qp);

  edge_v2<16><<<dim3(5, 128), dim3(512), SMEM_BYTES, stream>>>(A1b, A2b, W1f, b_l1, W2p, b_l2, pos, out);
  edge_v2<2><<<dim3(1, 128), dim3(512), SMEM_BYTES, stream>>>(A1b, A2b, W1f, b_l1, W2p, b_l2, pos, out);
}

// Round 3
// 163.257 us; speedup vs baseline: 2.1712x; 1.4236x over previous
//
#include <hip/hip_runtime.h>
#include <hip/hip_bf16.h>

typedef __attribute__((ext_vector_type(8))) short short8;
typedef __attribute__((ext_vector_type(4))) float f32x4;
typedef unsigned short u16;
typedef unsigned int u32;

__device__ __forceinline__ u16 f2b(float f) {
  __hip_bfloat16 h = __float2bfloat16(f);
  union { __hip_bfloat16 h; u16 u; } cv; cv.h = h; return cv.u;
}

__device__ __forceinline__ f32x4 mfma16(short8 a, short8 b, f32x4 c) {
  return __builtin_amdgcn_mfma_f32_16x16x32_bf16(a, b, c, 0, 0, 0);
}

__device__ __forceinline__ void gload_lds16(const void* g, void* l) {
  __builtin_amdgcn_global_load_lds(
      (const __attribute__((address_space(1))) void*)g,
      (__attribute__((address_space(3))) void*)l, 16, 0, 0);
}

// bf16-pair elementwise product
__device__ __forceinline__ u32 bmul2(u32 a, u32 b) {
  float al = __uint_as_float(a << 16);
  float ah = __uint_as_float(a & 0xffff0000u);
  float bl = __uint_as_float(b << 16);
  float bh = __uint_as_float(b & 0xffff0000u);
  return (u32)f2b(al * bl) | ((u32)f2b(ah * bh) << 16);
}

__device__ __forceinline__ short8 ld_frag8(const char* p) {
  uint2 a = *(const uint2*)(p);
  uint2 b = *(const uint2*)(p + 8);
  union { short8 s; u32 u[4]; } r;
  r.u[0] = a.x; r.u[1] = a.y; r.u[2] = b.x; r.u[3] = b.y;
  return r.s;
}

__device__ __forceinline__ short8 ld_frag16(const char* p) {
  union { short8 s; int4 v; } r;
  r.v = *(const int4*)(p);
  return r.s;
}

// ---- weight-norm prep ----
__global__ void wn_prep(const float* __restrict__ v, const float* __restrict__ g,
                        int K, int Nreal, u16* __restrict__ outW) {
  const int row = blockIdx.x;
  const int l = threadIdx.x;
  if (row >= Nreal) {
    for (int k = l; k < K; k += 64) outW[row * K + k] = 0;
    return;
  }
  const float* vr = v + (size_t)row * K;
  float ss = 0.f;
  for (int k = l * 4; k < K; k += 256) {
    f32x4 x = *(const f32x4*)(vr + k);
    ss += x.x * x.x + x.y * x.y + x.z * x.z + x.w * x.w;
  }
  #pragma unroll
  for (int m = 32; m >= 1; m >>= 1) ss += __shfl_xor(ss, m, 64);
  const float scale = g[row] / sqrtf(ss);
  for (int k = l; k < K; k += 64) outW[row * K + k] = f2b(vr[k] * scale);
}

// ---- W1 prep in chunk-fragment layout: W1f[kc(16)][row(256)][36] ----
__global__ void wn_prep_l1(const float* __restrict__ v, const float* __restrict__ g,
                           u16* __restrict__ W1f) {
  const int row = blockIdx.x;
  const int l = threadIdx.x;
  const float* vr = v + (size_t)row * 512;
  float ss = 0.f;
  for (int k = l * 4; k < 512; k += 256) {
    f32x4 x = *(const f32x4*)(vr + k);
    ss += x.x * x.x + x.y * x.y + x.z * x.z + x.w * x.w;
  }
  #pragma unroll
  for (int m = 32; m >= 1; m >>= 1) ss += __shfl_xor(ss, m, 64);
  const float scale = g[row] / sqrtf(ss);
  for (int c = l; c < 16 * 36; c += 64) {
    int kc = c / 36, el = c - kc * 36;
    u16 val = (el < 32) ? f2b(vr[kc * 32 + el] * scale) : (u16)0;
    W1f[kc * 9216 + row * 36 + el] = val;
  }
}

// ---- bulk fp32 -> bf16 convert ----
__global__ void cvt_bf16(const float* __restrict__ in, u16* __restrict__ out, int n) {
  const int i = (blockIdx.x * 256 + threadIdx.x) * 8;
  if (i >= n) return;
  f32x4 a = *(const f32x4*)(in + i);
  f32x4 b = *(const f32x4*)(in + i + 4);
  short8 r;
  r[0] = (short)f2b(a.x); r[1] = (short)f2b(a.y); r[2] = (short)f2b(a.z); r[3] = (short)f2b(a.w);
  r[4] = (short)f2b(b.x); r[5] = (short)f2b(b.y); r[6] = (short)f2b(b.z); r[7] = (short)f2b(b.w);
  *(short8*)(out + i) = r;
}

// ---- pos map ----
__global__ void pos_init(int* __restrict__ pos, int n) {
  int t = blockIdx.x * 256 + threadIdx.x;
  if (t < n) pos[t] = -1;
}
__global__ void pos_scatter(const int* __restrict__ indexes, int* __restrict__ pos, int n) {
  int m = blockIdx.x * 256 + threadIdx.x;
  if (m >= n) return;
  int idx = indexes[m];
  int bi = idx / 1296;
  int rem = idx - bi * 1296;
  pos[bi * 1312 + rem] = m;
}

// ================= LDS-staged stage-1 GEMM (m97-style) =================
// 128x128 tile, BK=64, 4 waves (2x2 of 64x64). global_load_lds staging with
// T2 XOR swizzle (inverse-swizzled global src, swizzled ds_read). 2-phase
// double-buffered pipeline: raw s_barrier + vmcnt so next-tile loads fly
// under current MFMA (1 block/CU -> no TLP to hide latency otherwise).
// MODE 0: fp32 partials out (split-K over blockIdx.z, K-chunk = 128).
// MODE 1: o_a2 = bf16(C+bias), o_a1 = bf16((C+bias)*qp).
template <int MODE>
__global__ __launch_bounds__(256, 2) void gemm_lds(
    const u16* __restrict__ Ab, const u16* __restrict__ Wb,
    int K, int nstep, const float* __restrict__ bias,
    float* __restrict__ fout, u16* __restrict__ o_a2, u16* __restrict__ o_a1,
    const float* __restrict__ qp) {
  __shared__ char smem[2][2][16384];   // [buf][A/B][128 rows x 128 B]
  const int t = threadIdx.x, l = t & 63, w = t >> 6;
  const int lr = l & 15, lg = l >> 4;
  const int wm = w & 1, wn2 = w >> 1;
  const int bm = blockIdx.x * 128, bn = blockIdx.y * 128;
  const int kbase = (MODE == 0) ? blockIdx.z * 128 : 0;
  const int ldb = K * 2;

  const char* Abase = (const char*)(Ab + (size_t)bm * K + kbase);
  const char* Bbase = (const char*)(Wb + (size_t)bn * K + kbase);

  auto stage = [&](int buf, int ks) {
    const char* asrc = Abase + ks * 128;
    const char* bsrc = Bbase + ks * 128;
    #pragma unroll
    for (int it = 0; it < 4; it++) {
      const int c = it * 256 + w * 64 + l;
      const int row = c >> 3;
      const int cb = ((c & 7) * 16) ^ ((row & 7) << 4);   // inverse-swizzled src col
      char* adst = &smem[buf][0][(it * 256 + w * 64) * 16];
      char* bdst = &smem[buf][1][(it * 256 + w * 64) * 16];
      gload_lds16(asrc + (size_t)row * ldb + cb, adst);
      gload_lds16(bsrc + (size_t)row * ldb + cb, bdst);
    }
  };

  stage(0, 0);
  asm volatile("s_waitcnt vmcnt(0)" ::: "memory");
  __builtin_amdgcn_s_barrier();

  f32x4 acc[4][4] = {};
  for (int ks = 0; ks < nstep; ks++) {
    const int cur = ks & 1;
    if (ks + 1 < nstep) stage(cur ^ 1, ks + 1);
    const char* As = smem[cur][0];
    const char* Bs = smem[cur][1];
    #pragma unroll
    for (int kk = 0; kk < 2; kk++) {
      short8 af[4], bf[4];
      #pragma unroll
      for (int m = 0; m < 4; m++) {
        const int r = wm * 64 + m * 16 + lr;
        af[m] = ld_frag16(As + r * 128 + ((kk * 64 + lg * 16) ^ ((lr & 7) << 4)));
      }
      #pragma unroll
      for (int n = 0; n < 4; n++) {
        const int r = wn2 * 64 + n * 16 + lr;
        bf[n] = ld_frag16(Bs + r * 128 + ((kk * 64 + lg * 16) ^ ((lr & 7) << 4)));
      }
      #pragma unroll
      for (int m = 0; m < 4; m++)
        #pragma unroll
        for (int n = 0; n < 4; n++)
          acc[m][n] = mfma16(af[m], bf[n], acc[m][n]);
    }
    asm volatile("s_waitcnt vmcnt(0)" ::: "memory");
    __builtin_amdgcn_s_barrier();
  }

  #pragma unroll
  for (int n = 0; n < 4; n++) {
    const int c = bn + wn2 * 64 + n * 16 + lr;
    const float bv = (MODE == 1) ? bias[c] : 0.f;
    #pragma unroll
    for (int m = 0; m < 4; m++) {
      #pragma unroll
      for (int q = 0; q < 4; q++) {
        const int r = bm + wm * 64 + m * 16 + lg * 4 + q;
        const float val = acc[m][n][q];
        if (MODE == 0) {
          fout[((size_t)blockIdx.z * 128 + r) * 512 + c] = val;
        } else {
          const float vb = val + bv;
          o_a2[(size_t)r * 512 + c] = f2b(vb);
          o_a1[(size_t)r * 512 + c] = f2b(vb * qp[(r / 36) * 512 + c]);
        }
      }
    }
  }
}

// ---- split-K reduce for qp: qp = sum_s part[s] + b_q ----
__global__ void qp_reduce(const float* __restrict__ part, const float* __restrict__ bq,
                          float* __restrict__ qp) {
  const int i = (blockIdx.x * 256 + threadIdx.x) * 4;
  f32x4 s = *(const f32x4*)(part + i);
  #pragma unroll
  for (int k = 1; k < 8; k++) {
    f32x4 v = *(const f32x4*)(part + (size_t)k * 65536 + i);
    s.x += v.x; s.y += v.y; s.z += v.z; s.w += v.w;
  }
  const int c = i & 511;
  s.x += bq[c]; s.y += bq[c + 1]; s.z += bq[c + 2]; s.w += bq[c + 3];
  *(f32x4*)(qp + i) = s;
}

// ================= fused edge kernel (unchanged from R2) =================
#define OFF_A1 0
#define OFF_A2 37440
#define OFF_EC 74880
#define OFF_W1 119936
#define SMEM_BYTES 156800

template <int MT>
__global__ __launch_bounds__(512, 2) void edge_v2(
    const u16* __restrict__ A1g, const u16* __restrict__ A2g,
    const u16* __restrict__ W1f, const float* __restrict__ b1,
    const u16* __restrict__ W2p, const float* __restrict__ b2,
    const int* __restrict__ pos, float* __restrict__ out) {
  extern __shared__ char smem[];
  const int t = threadIdx.x, l = t & 63, w = t >> 6;
  const int lr = l & 15, lg = l >> 4;
  const int wm = w >> 2, wn = w & 3;
  const int MT_W = MT / 2;

  const int bi = blockIdx.y;
  const int mb = (MT == 16) ? blockIdx.x * 256 : 1280;

  #pragma unroll
  for (int it = 0; it < 9; it++) {
    int c = t + it * 512;
    int rr = c >> 6, off = c & 63;
    const u16* src = (rr < 36) ? (A1g + (size_t)(bi * 36 + rr) * 512 + off * 8)
                               : (A2g + (size_t)(bi * 36 + rr - 36) * 512 + off * 8);
    char* dst = smem + ((rr < 36) ? (OFF_A1 + rr * 1040) : (OFF_A2 + (rr - 36) * 1040)) + off * 16;
    *(int4*)dst = *(const int4*)src;
  }
  #pragma unroll
  for (int it = 0; it < 3; it++) {
    int c = t + it * 512;
    if (c < 1152) *(int4*)(smem + OFF_W1 + c * 16) = *(const int4*)(W1f + c * 8);
  }
  __syncthreads();

  const int erow = t >> 1;
  const int brow = mb + erow;
  const int ii = brow / 36;
  const int jj = brow - ii * 36;
  const char* a1base = smem + OFF_A1 + ii * 1040 + (t & 1) * 32;
  const char* a2base = smem + OFF_A2 + jj * 1040 + (t & 1) * 32;
  char* ecbase = smem + OFF_EC + erow * 88 + (t & 1) * 32;
  const bool egen_on = (erow < MT * 16);

  if (egen_on) {
    int4 x0 = *(const int4*)(a1base);
    int4 x1 = *(const int4*)(a1base + 16);
    int4 y0 = *(const int4*)(a2base);
    int4 y1 = *(const int4*)(a2base + 16);
    u32 e0 = bmul2(x0.x, y0.x), e1 = bmul2(x0.y, y0.y), e2 = bmul2(x0.z, y0.z), e3 = bmul2(x0.w, y0.w);
    u32 e4 = bmul2(x1.x, y1.x), e5 = bmul2(x1.y, y1.y), e6 = bmul2(x1.z, y1.z), e7 = bmul2(x1.w, y1.w);
    *(uint2*)(ecbase)      = make_uint2(e0, e1);
    *(uint2*)(ecbase + 8)  = make_uint2(e2, e3);
    *(uint2*)(ecbase + 16) = make_uint2(e4, e5);
    *(uint2*)(ecbase + 24) = make_uint2(e6, e7);
  }
  __syncthreads();

  float b1v[4];
  #pragma unroll
  for (int n = 0; n < 4; n++) b1v[n] = b1[wn * 64 + n * 16 + lr];

  f32x4 acc[MT_W > 0 ? MT_W : 1][4] = {};

  for (int kc = 0; kc < 16; kc++) {
    const int cur = kc & 1, nxt = cur ^ 1;
    const bool more = (kc < 15);

    int4 sreg0, sreg1, sreg2;
    if (more) {
      const u16* wsrc = W1f + (size_t)(kc + 1) * 9216;
      sreg0 = *(const int4*)(wsrc + (t) * 8);
      sreg1 = *(const int4*)(wsrc + (t + 512) * 8);
      if (t < 128) sreg2 = *(const int4*)(wsrc + (t + 1024) * 8);
    }
    if (more && egen_on) {
      const char* p1 = a1base + (kc + 1) * 64;
      const char* p2 = a2base + (kc + 1) * 64;
      int4 x0 = *(const int4*)(p1);
      int4 x1 = *(const int4*)(p1 + 16);
      int4 y0 = *(const int4*)(p2);
      int4 y1 = *(const int4*)(p2 + 16);
      u32 e0 = bmul2(x0.x, y0.x), e1 = bmul2(x0.y, y0.y), e2 = bmul2(x0.z, y0.z), e3 = bmul2(x0.w, y0.w);
      u32 e4 = bmul2(x1.x, y1.x), e5 = bmul2(x1.y, y1.y), e6 = bmul2(x1.z, y1.z), e7 = bmul2(x1.w, y1.w);
      char* eo = ecbase + nxt * 22528;
      *(uint2*)(eo)      = make_uint2(e0, e1);
      *(uint2*)(eo + 8)  = make_uint2(e2, e3);
      *(uint2*)(eo + 16) = make_uint2(e4, e5);
      *(uint2*)(eo + 24) = make_uint2(e6, e7);
    }
    {
      const char* ecr = smem + OFF_EC + cur * 22528;
      const char* w1r = smem + OFF_W1 + cur * 18432;
      short8 bfr[4];
      #pragma unroll
      for (int n = 0; n < 4; n++)
        bfr[n] = ld_frag8(w1r + (wn * 64 + n * 16 + lr) * 72 + lg * 16);
      #pragma unroll
      for (int m = 0; m < MT_W; m++) {
        short8 af = ld_frag8(ecr + ((wm * MT_W + m) * 16 + lr) * 88 + lg * 16);
        #pragma unroll
        for (int n = 0; n < 4; n++)
          acc[m][n] = mfma16(af, bfr[n], acc[m][n]);
      }
    }
    if (more) {
      char* wdst = smem + OFF_W1 + nxt * 18432;
      *(int4*)(wdst + t * 16) = sreg0;
      *(int4*)(wdst + (t + 512) * 16) = sreg1;
      if (t < 128) *(int4*)(wdst + (t + 1024) * 16) = sreg2;
    }
    __syncthreads();
  }

  #pragma unroll
  for (int m = 0; m < MT_W; m++) {
    #pragma unroll
    for (int n = 0; n < 4; n++) {
      const int c = wn * 64 + n * 16 + lr;
      #pragma unroll
      for (int q = 0; q < 4; q++) {
        const int r = (wm * MT_W + m) * 16 + lg * 4 + q;
        *(u16*)(smem + r * 528 + c * 2) = f2b(fmaxf(acc[m][n][q] + b1v[n], 0.f));
      }
    }
  }
  __syncthreads();

  short8 bfr2[8];
  #pragma unroll
  for (int kk = 0; kk < 8; kk++)
    bfr2[kk] = ld_frag16((const char*)(W2p + lr * 256 + kk * 32 + lg * 8));

  const int T2 = (MT + 7) / 8;
  #pragma unroll
  for (int tt = 0; tt < T2; tt++) {
    const int tile = w * T2 + tt;
    if (tile < MT) {
      f32x4 a2c = {0.f, 0.f, 0.f, 0.f};
      #pragma unroll
      for (int kk = 0; kk < 8; kk++) {
        short8 af = ld_frag16(smem + (tile * 16 + lr) * 528 + kk * 64 + lg * 16);
        a2c = mfma16(af, bfr2[kk], a2c);
      }
      if (lr < 8) {
        const float b2v = b2[lr];
        #pragma unroll
        for (int q = 0; q < 4; q++) {
          const int rl = tile * 16 + lg * 4 + q;
          const int m = pos[bi * 1312 + mb + rl];
          if (m >= 0) out[(size_t)m * 8 + lr] = a2c[q] + b2v;
        }
      }
    }
  }
}

extern "C" void kernel_launch(void* const* d_in, const int* in_sizes, int n_in,
                              void* d_out, int out_size, void* d_ws, size_t ws_size,
                              hipStream_t stream) {
  const float* node_feats = (const float*)d_in[0];
  const float* q_feats    = (const float*)d_in[1];
  const int*   indexes    = (const int*)d_in[2];
  const float* v_obj = (const float*)d_in[3];
  const float* g_obj = (const float*)d_in[4];
  const float* b_obj = (const float*)d_in[5];
  const float* v_q   = (const float*)d_in[6];
  const float* g_q   = (const float*)d_in[7];
  const float* b_q   = (const float*)d_in[8];
  const float* v_l1  = (const float*)d_in[9];
  const float* g_l1  = (const float*)d_in[10];
  const float* b_l1  = (const float*)d_in[11];
  const float* v_l2  = (const float*)d_in[12];
  const float* g_l2  = (const float*)d_in[13];
  const float* b_l2  = (const float*)d_in[14];
  float* out = (float*)d_out;

  char* ws = (char*)d_ws;
  u16*   node_b = (u16*)(ws + 0);               // 18,874,368
  u16*   q_b    = (u16*)(ws + 18874368);        //    262,144
  u16*   Wobjb  = (u16*)(ws + 19136512);        //  2,097,152
  u16*   Wqb    = (u16*)(ws + 21233664);        //  1,048,576
  u16*   W1f    = (u16*)(ws + 22282240);        //    294,912
  u16*   W2p    = (u16*)(ws + 22577152);        //      8,192
  float* qp     = (float*)(ws + 22585344);      //    262,144
  u16*   A1b    = (u16*)(ws + 22847488);        //  4,718,592
  u16*   A2b    = (u16*)(ws + 27566080);        //  4,718,592
  int*   pos    = (int*)(ws + 32284672);        //    671,744
  float* part   = (float*)(ws + 32956416);      //  2,097,152 (8 x 128 x 512 fp32)

  wn_prep<<<dim3(512), dim3(64), 0, stream>>>(v_obj, g_obj, 2048, 512, Wobjb);
  wn_prep<<<dim3(512), dim3(64), 0, stream>>>(v_q,   g_q,   1024, 512, Wqb);
  wn_prep_l1<<<dim3(256), dim3(64), 0, stream>>>(v_l1, g_l1, W1f);
  wn_prep<<<dim3(16),  dim3(64), 0, stream>>>(v_l2,  g_l2,  256,  8,   W2p);

  cvt_bf16<<<dim3(4608), dim3(256), 0, stream>>>(node_feats, node_b, 9437184);
  cvt_bf16<<<dim3(64),   dim3(256), 0, stream>>>(q_feats,    q_b,    131072);

  pos_init<<<dim3(656), dim3(256), 0, stream>>>(pos, 128 * 1312);
  pos_scatter<<<dim3(630), dim3(256), 0, stream>>>(indexes, pos, 161280);

  // qp = q @ Wq^T + b_q via split-K(8) + reduce
  gemm_lds<0><<<dim3(1, 4, 8), dim3(256), 0, stream>>>(q_b, Wqb, 1024, 2, nullptr,
                                                       part, nullptr, nullptr, nullptr);
  qp_reduce<<<dim3(64), dim3(256), 0, stream>>>(part, b_q, qp);

  // nf GEMM: A2 = bf16(nf), A1 = bf16(nf * qp)
  gemm_lds<1><<<dim3(36, 4), dim3(256), 0, stream>>>(node_b, Wobjb, 2048, 32, b_obj,
                                                     nullptr, A2b, A1b, qp);

  edge_v2<16><<<dim3(5, 128), dim3(512), SMEM_BYTES, stream>>>(A1b, A2b, W1f, b_l1, W2p, b_l2, pos, out);
  edge_v2<2><<<dim3(1, 128), dim3(512), SMEM_BYTES, stream>>>(A1b, A2b, W1f, b_l1, W2p, b_l2, pos, out);
}

// Round 4
// 147.772 us; speedup vs baseline: 2.3987x; 1.1048x over previous
//
#include <hip/hip_runtime.h>
#include <hip/hip_bf16.h>

typedef __attribute__((ext_vector_type(8))) short short8;
typedef __attribute__((ext_vector_type(4))) float f32x4;
typedef unsigned short u16;
typedef unsigned int u32;

__device__ __forceinline__ u16 f2b(float f) {
  __hip_bfloat16 h = __float2bfloat16(f);
  union { __hip_bfloat16 h; u16 u; } cv; cv.h = h; return cv.u;
}

__device__ __forceinline__ f32x4 mfma16(short8 a, short8 b, f32x4 c) {
  return __builtin_amdgcn_mfma_f32_16x16x32_bf16(a, b, c, 0, 0, 0);
}

__device__ __forceinline__ void gload_lds16(const void* g, void* l) {
  __builtin_amdgcn_global_load_lds(
      (const __attribute__((address_space(1))) void*)g,
      (__attribute__((address_space(3))) void*)l, 16, 0, 0);
}

// packed f32x2 -> bf16x2 with RNE (single instruction on gfx950)
__device__ __forceinline__ u32 cvtpk(float lo, float hi) {
  u32 r;
  asm("v_cvt_pk_bf16_f32 %0, %1, %2" : "=v"(r) : "v"(lo), "v"(hi));
  return r;
}

// bf16-pair product: (a.lo*b.lo, a.hi*b.hi) -> packed bf16 pair (RNE via cvt_pk)
__device__ __forceinline__ u32 bmul2(u32 a, u32 b) {
  float al = __uint_as_float(a << 16);
  float ah = __uint_as_float(a & 0xffff0000u);
  float bl = __uint_as_float(b << 16);
  float bh = __uint_as_float(b & 0xffff0000u);
  return cvtpk(al * bl, ah * bh);
}

__device__ __forceinline__ short8 ld_frag8(const char* p) {
  uint2 a = *(const uint2*)(p);
  uint2 b = *(const uint2*)(p + 8);
  union { short8 s; u32 u[4]; } r;
  r.u[0] = a.x; r.u[1] = a.y; r.u[2] = b.x; r.u[3] = b.y;
  return r.s;
}

__device__ __forceinline__ short8 ld_frag16(const char* p) {
  union { short8 s; int4 v; } r;
  r.v = *(const int4*)(p);
  return r.s;
}

// ---- weight-norm prep ----
__global__ void wn_prep(const float* __restrict__ v, const float* __restrict__ g,
                        int K, int Nreal, u16* __restrict__ outW) {
  const int row = blockIdx.x;
  const int l = threadIdx.x;
  if (row >= Nreal) {
    for (int k = l; k < K; k += 64) outW[row * K + k] = 0;
    return;
  }
  const float* vr = v + (size_t)row * K;
  float ss = 0.f;
  for (int k = l * 4; k < K; k += 256) {
    f32x4 x = *(const f32x4*)(vr + k);
    ss += x.x * x.x + x.y * x.y + x.z * x.z + x.w * x.w;
  }
  #pragma unroll
  for (int m = 32; m >= 1; m >>= 1) ss += __shfl_xor(ss, m, 64);
  const float scale = g[row] / sqrtf(ss);
  for (int k = l; k < K; k += 64) outW[row * K + k] = f2b(vr[k] * scale);
}

// ---- W1 prep in chunk-fragment layout: W1f[kc(16)][row(256)][36] ----
__global__ void wn_prep_l1(const float* __restrict__ v, const float* __restrict__ g,
                           u16* __restrict__ W1f) {
  const int row = blockIdx.x;
  const int l = threadIdx.x;
  const float* vr = v + (size_t)row * 512;
  float ss = 0.f;
  for (int k = l * 4; k < 512; k += 256) {
    f32x4 x = *(const f32x4*)(vr + k);
    ss += x.x * x.x + x.y * x.y + x.z * x.z + x.w * x.w;
  }
  #pragma unroll
  for (int m = 32; m >= 1; m >>= 1) ss += __shfl_xor(ss, m, 64);
  const float scale = g[row] / sqrtf(ss);
  for (int c = l; c < 16 * 36; c += 64) {
    int kc = c / 36, el = c - kc * 36;
    u16 val = (el < 32) ? f2b(vr[kc * 32 + el] * scale) : (u16)0;
    W1f[kc * 9216 + row * 36 + el] = val;
  }
}

// ---- bulk fp32 -> bf16 convert ----
__global__ void cvt_bf16(const float* __restrict__ in, u16* __restrict__ out, int n) {
  const int i = (blockIdx.x * 256 + threadIdx.x) * 8;
  if (i >= n) return;
  f32x4 a = *(const f32x4*)(in + i);
  f32x4 b = *(const f32x4*)(in + i + 4);
  union { short8 s; u32 u[4]; } r;
  r.u[0] = cvtpk(a.x, a.y); r.u[1] = cvtpk(a.z, a.w);
  r.u[2] = cvtpk(b.x, b.y); r.u[3] = cvtpk(b.z, b.w);
  *(short8*)(out + i) = r.s;
}

// ---- pos map ----
__global__ void pos_init(int* __restrict__ pos, int n) {
  int t = blockIdx.x * 256 + threadIdx.x;
  if (t < n) pos[t] = -1;
}
__global__ void pos_scatter(const int* __restrict__ indexes, int* __restrict__ pos, int n) {
  int m = blockIdx.x * 256 + threadIdx.x;
  if (m >= n) return;
  int idx = indexes[m];
  int bi = idx / 1296;
  int rem = idx - bi * 1296;
  pos[bi * 1312 + rem] = m;
}

// ================= LDS-staged stage-1 GEMM (unchanged from R3) =================
template <int MODE>
__global__ __launch_bounds__(256, 2) void gemm_lds(
    const u16* __restrict__ Ab, const u16* __restrict__ Wb,
    int K, int nstep, const float* __restrict__ bias,
    float* __restrict__ fout, u16* __restrict__ o_a2, u16* __restrict__ o_a1,
    const float* __restrict__ qp) {
  __shared__ char smem[2][2][16384];
  const int t = threadIdx.x, l = t & 63, w = t >> 6;
  const int lr = l & 15, lg = l >> 4;
  const int wm = w & 1, wn2 = w >> 1;
  const int bm = blockIdx.x * 128, bn = blockIdx.y * 128;
  const int kbase = (MODE == 0) ? blockIdx.z * 128 : 0;
  const int ldb = K * 2;

  const char* Abase = (const char*)(Ab + (size_t)bm * K + kbase);
  const char* Bbase = (const char*)(Wb + (size_t)bn * K + kbase);

  auto stage = [&](int buf, int ks) {
    const char* asrc = Abase + ks * 128;
    const char* bsrc = Bbase + ks * 128;
    #pragma unroll
    for (int it = 0; it < 4; it++) {
      const int c = it * 256 + w * 64 + l;
      const int row = c >> 3;
      const int cb = ((c & 7) * 16) ^ ((row & 7) << 4);
      char* adst = &smem[buf][0][(it * 256 + w * 64) * 16];
      char* bdst = &smem[buf][1][(it * 256 + w * 64) * 16];
      gload_lds16(asrc + (size_t)row * ldb + cb, adst);
      gload_lds16(bsrc + (size_t)row * ldb + cb, bdst);
    }
  };

  stage(0, 0);
  asm volatile("s_waitcnt vmcnt(0)" ::: "memory");
  __builtin_amdgcn_s_barrier();

  f32x4 acc[4][4] = {};
  for (int ks = 0; ks < nstep; ks++) {
    const int cur = ks & 1;
    if (ks + 1 < nstep) stage(cur ^ 1, ks + 1);
    const char* As = smem[cur][0];
    const char* Bs = smem[cur][1];
    #pragma unroll
    for (int kk = 0; kk < 2; kk++) {
      short8 af[4], bf[4];
      #pragma unroll
      for (int m = 0; m < 4; m++) {
        const int r = wm * 64 + m * 16 + lr;
        af[m] = ld_frag16(As + r * 128 + ((kk * 64 + lg * 16) ^ ((lr & 7) << 4)));
      }
      #pragma unroll
      for (int n = 0; n < 4; n++) {
        const int r = wn2 * 64 + n * 16 + lr;
        bf[n] = ld_frag16(Bs + r * 128 + ((kk * 64 + lg * 16) ^ ((lr & 7) << 4)));
      }
      #pragma unroll
      for (int m = 0; m < 4; m++)
        #pragma unroll
        for (int n = 0; n < 4; n++)
          acc[m][n] = mfma16(af[m], bf[n], acc[m][n]);
    }
    asm volatile("s_waitcnt vmcnt(0)" ::: "memory");
    __builtin_amdgcn_s_barrier();
  }

  #pragma unroll
  for (int n = 0; n < 4; n++) {
    const int c = bn + wn2 * 64 + n * 16 + lr;
    const float bv = (MODE == 1) ? bias[c] : 0.f;
    #pragma unroll
    for (int m = 0; m < 4; m++) {
      #pragma unroll
      for (int q = 0; q < 4; q++) {
        const int r = bm + wm * 64 + m * 16 + lg * 4 + q;
        const float val = acc[m][n][q];
        if (MODE == 0) {
          fout[((size_t)blockIdx.z * 128 + r) * 512 + c] = val;
        } else {
          const float vb = val + bv;
          o_a2[(size_t)r * 512 + c] = f2b(vb);
          o_a1[(size_t)r * 512 + c] = f2b(vb * qp[(r / 36) * 512 + c]);
        }
      }
    }
  }
}

// ---- split-K reduce for qp ----
__global__ void qp_reduce(const float* __restrict__ part, const float* __restrict__ bq,
                          float* __restrict__ qp) {
  const int i = (blockIdx.x * 256 + threadIdx.x) * 4;
  f32x4 s = *(const f32x4*)(part + i);
  #pragma unroll
  for (int k = 1; k < 8; k++) {
    f32x4 v = *(const f32x4*)(part + (size_t)k * 65536 + i);
    s.x += v.x; s.y += v.y; s.z += v.z; s.w += v.w;
  }
  const int c = i & 511;
  s.x += bq[c]; s.y += bq[c + 1]; s.z += bq[c + 2]; s.w += bq[c + 3];
  *(f32x4*)(qp + i) = s;
}

// ================= fused edge kernel v3 =================
// Block = one batch bi x 144 rows (mb = 144*bx, exactly 4 i-values, no tail).
// LDS: A1 4x1040 | A2 36x1040 | Ec dbuf 2x[144][36]u16 | W1 single [256][36]u16
//  = 80768 B -> 2 blocks/CU (16 waves/CU).
// Per kc: W1(kc+1) global->reg (T14) || E-gen(kc+1)->Ec[nxt] || MFMA(kc);
//         barrier; reg->W1 LDS; barrier.
#define OFF_A1 0
#define OFF_A2 4160
#define OFF_EC 41600          // 2 x 144*72 = 2 x 10368
#define OFF_W1 62336          // 256*72 = 18432
#define EDGE_SMEM 80768

__global__ __launch_bounds__(512, 4) void edge_v3(
    const u16* __restrict__ A1g, const u16* __restrict__ A2g,
    const u16* __restrict__ W1f, const float* __restrict__ b1,
    const u16* __restrict__ W2p, const float* __restrict__ b2,
    const int* __restrict__ pos, float* __restrict__ out) {
  extern __shared__ char smem[];
  const int t = threadIdx.x, l = t & 63, w = t >> 6;
  const int lr = l & 15, lg = l >> 4;
  const int bi = blockIdx.y;
  const int mb = blockIdx.x * 144;
  const int i0 = blockIdx.x * 4;

  // ---- stage A1 (4 rows) + A2 (36 rows), stride 1040; wave w -> rows w,w+8,... ----
  for (int r = w; r < 40; r += 8) {
    const u16* src = (r < 4) ? (A1g + (size_t)(bi * 36 + i0 + r) * 512 + l * 8)
                             : (A2g + (size_t)(bi * 36 + (r - 4)) * 512 + l * 8);
    char* dst = smem + ((r < 4) ? (OFF_A1 + r * 1040) : (OFF_A2 + (r - 4) * 1040)) + l * 16;
    *(int4*)dst = *(const int4*)src;
  }
  // ---- W1 chunk 0 -> LDS (global->reg->LDS, covered by prologue barrier) ----
  {
    int4 s0 = *(const int4*)(W1f + t * 8);
    int4 s1 = *(const int4*)(W1f + (t + 512) * 8);
    int4 s2;
    if (t < 128) s2 = *(const int4*)(W1f + (t + 1024) * 8);
    *(int4*)(smem + OFF_W1 + t * 16) = s0;
    *(int4*)(smem + OFF_W1 + (t + 512) * 16) = s1;
    if (t < 128) *(int4*)(smem + OFF_W1 + (t + 1024) * 16) = s2;
  }

  // ---- E-gen granule setup: 576 granules of 16B (4 els); g0 = t, g1 = 512+t (t<64) ----
  const int g0row = t >> 2, g0c = (t & 3) * 16;
  const int ii0 = g0row / 36, jj0 = g0row - ii0 * 36;
  const char* a1p0 = smem + OFF_A1 + ii0 * 1040 + g0c;
  const char* a2p0 = smem + OFF_A2 + jj0 * 1040 + g0c;
  char* ecp0 = smem + OFF_EC + g0row * 72 + g0c;
  const int g1row = 128 + (t >> 2), g1c = g0c;
  const int jj1 = g1row - 108;                       // ii1 == 3
  const char* a1p1 = smem + OFF_A1 + 3 * 1040 + g1c;
  const char* a2p1 = smem + OFF_A2 + jj1 * 1040 + g1c;
  char* ecp1 = smem + OFF_EC + g1row * 72 + g1c;

  auto egen = [&](int kc, int buf) {
    const int kb = kc * 64;
    const int bo = buf * 10368;
    {
      uint4 x = *(const uint4*)(a1p0 + kb);
      uint4 y = *(const uint4*)(a2p0 + kb);
      u32 e0 = bmul2(x.x, y.x), e1 = bmul2(x.y, y.y);
      u32 e2 = bmul2(x.z, y.z), e3 = bmul2(x.w, y.w);
      *(uint2*)(ecp0 + bo) = make_uint2(e0, e1);
      *(uint2*)(ecp0 + bo + 8) = make_uint2(e2, e3);
    }
    if (t < 64) {
      uint4 x = *(const uint4*)(a1p1 + kb);
      uint4 y = *(const uint4*)(a2p1 + kb);
      u32 e0 = bmul2(x.x, y.x), e1 = bmul2(x.y, y.y);
      u32 e2 = bmul2(x.z, y.z), e3 = bmul2(x.w, y.w);
      *(uint2*)(ecp1 + bo) = make_uint2(e0, e1);
      *(uint2*)(ecp1 + bo + 8) = make_uint2(e2, e3);
    }
  };

  __syncthreads();      // A-tables + W1(0) ready
  egen(0, 0);
  __syncthreads();      // Ec[0] ready

  const float b1v0 = b1[w * 32 + lr];
  const float b1v1 = b1[w * 32 + 16 + lr];

  f32x4 acc[9][2] = {};
  int cur = 0;

  for (int kc = 0; kc < 16; kc++) {
    const bool more = (kc < 15);
    int4 s0, s1, s2;
    if (more) {                              // T14: issue W1(kc+1) loads early
      const u16* ws = W1f + (size_t)(kc + 1) * 9216;
      s0 = *(const int4*)(ws + t * 8);
      s1 = *(const int4*)(ws + (t + 512) * 8);
      if (t < 128) s2 = *(const int4*)(ws + (t + 1024) * 8);
    }
    if (more) egen(kc + 1, cur ^ 1);

    // MFMA(kc): wave w -> cols [w*32, w*32+32), all 9 M-tiles
    {
      const char* w1b = smem + OFF_W1;
      const char* ecb = smem + OFF_EC + cur * 10368;
      short8 bfr0 = ld_frag8(w1b + (w * 32 + lr) * 72 + lg * 16);
      short8 bfr1 = ld_frag8(w1b + (w * 32 + 16 + lr) * 72 + lg * 16);
      #pragma unroll
      for (int m = 0; m < 9; m++) {
        short8 af = ld_frag8(ecb + (m * 16 + lr) * 72 + lg * 16);
        acc[m][0] = mfma16(af, bfr0, acc[m][0]);
        acc[m][1] = mfma16(af, bfr1, acc[m][1]);
      }
    }
    __syncthreads();                         // W1buf reads + Ec[cur] reads done
    if (more) {
      *(int4*)(smem + OFF_W1 + t * 16) = s0;
      *(int4*)(smem + OFF_W1 + (t + 512) * 16) = s1;
      if (t < 128) *(int4*)(smem + OFF_W1 + (t + 1024) * 16) = s2;
    }
    __syncthreads();                         // W1(kc+1) ready
    cur ^= 1;
  }

  // ---- epilogue 1: bias + relu -> bf16 h tile [144][264]u16 (aliases A/Ec/W1) ----
  #pragma unroll
  for (int m = 0; m < 9; m++) {
    #pragma unroll
    for (int n = 0; n < 2; n++) {
      const int c = w * 32 + n * 16 + lr;
      const float bv = (n == 0) ? b1v0 : b1v1;
      #pragma unroll
      for (int qq = 0; qq < 2; qq++) {
        const float v0 = fmaxf(acc[m][n][2 * qq] + bv, 0.f);
        const float v1 = fmaxf(acc[m][n][2 * qq + 1] + bv, 0.f);
        const u32 p = cvtpk(v0, v1);
        const int r = m * 16 + lg * 4 + 2 * qq;
        *(u16*)(smem + r * 528 + c * 2) = (u16)p;
        *(u16*)(smem + (r + 1) * 528 + c * 2) = (u16)(p >> 16);
      }
    }
  }
  __syncthreads();

  // ---- GEMM2: out = h @ W2p^T + b2, K=256; 9 tiles over 8 waves ----
  short8 bfr2[8];
  #pragma unroll
  for (int kk = 0; kk < 8; kk++)
    bfr2[kk] = ld_frag16((const char*)(W2p + lr * 256 + kk * 32 + lg * 8));

  #pragma unroll
  for (int tt = 0; tt < 2; tt++) {
    const int tile = tt * 8 + w;
    if (tile < 9) {
      f32x4 a2c = {0.f, 0.f, 0.f, 0.f};
      #pragma unroll
      for (int kk = 0; kk < 8; kk++) {
        short8 af = ld_frag16(smem + (tile * 16 + lr) * 528 + kk * 64 + lg * 16);
        a2c = mfma16(af, bfr2[kk], a2c);
      }
      if (lr < 8) {
        const float b2v = b2[lr];
        #pragma unroll
        for (int q = 0; q < 4; q++) {
          const int rl = tile * 16 + lg * 4 + q;
          const int m = pos[bi * 1312 + mb + rl];
          if (m >= 0) out[(size_t)m * 8 + lr] = a2c[q] + b2v;
        }
      }
    }
  }
}

extern "C" void kernel_launch(void* const* d_in, const int* in_sizes, int n_in,
                              void* d_out, int out_size, void* d_ws, size_t ws_size,
                              hipStream_t stream) {
  const float* node_feats = (const float*)d_in[0];
  const float* q_feats    = (const float*)d_in[1];
  const int*   indexes    = (const int*)d_in[2];
  const float* v_obj = (const float*)d_in[3];
  const float* g_obj = (const float*)d_in[4];
  const float* b_obj = (const float*)d_in[5];
  const float* v_q   = (const float*)d_in[6];
  const float* g_q   = (const float*)d_in[7];
  const float* b_q   = (const float*)d_in[8];
  const float* v_l1  = (const float*)d_in[9];
  const float* g_l1  = (const float*)d_in[10];
  const float* b_l1  = (const float*)d_in[11];
  const float* v_l2  = (const float*)d_in[12];
  const float* g_l2  = (const float*)d_in[13];
  const float* b_l2  = (const float*)d_in[14];
  float* out = (float*)d_out;

  char* ws = (char*)d_ws;
  u16*   node_b = (u16*)(ws + 0);               // 18,874,368
  u16*   q_b    = (u16*)(ws + 18874368);        //    262,144
  u16*   Wobjb  = (u16*)(ws + 19136512);        //  2,097,152
  u16*   Wqb    = (u16*)(ws + 21233664);        //  1,048,576
  u16*   W1f    = (u16*)(ws + 22282240);        //    294,912
  u16*   W2p    = (u16*)(ws + 22577152);        //      8,192
  float* qp     = (float*)(ws + 22585344);      //    262,144
  u16*   A1b    = (u16*)(ws + 22847488);        //  4,718,592
  u16*   A2b    = (u16*)(ws + 27566080);        //  4,718,592
  int*   pos    = (int*)(ws + 32284672);        //    671,744
  float* part   = (float*)(ws + 32956416);      //  2,097,152

  wn_prep<<<dim3(512), dim3(64), 0, stream>>>(v_obj, g_obj, 2048, 512, Wobjb);
  wn_prep<<<dim3(512), dim3(64), 0, stream>>>(v_q,   g_q,   1024, 512, Wqb);
  wn_prep_l1<<<dim3(256), dim3(64), 0, stream>>>(v_l1, g_l1, W1f);
  wn_prep<<<dim3(16),  dim3(64), 0, stream>>>(v_l2,  g_l2,  256,  8,   W2p);

  cvt_bf16<<<dim3(4608), dim3(256), 0, stream>>>(node_feats, node_b, 9437184);
  cvt_bf16<<<dim3(64),   dim3(256), 0, stream>>>(q_feats,    q_b,    131072);

  pos_init<<<dim3(656), dim3(256), 0, stream>>>(pos, 128 * 1312);
  pos_scatter<<<dim3(630), dim3(256), 0, stream>>>(indexes, pos, 161280);

  gemm_lds<0><<<dim3(1, 4, 8), dim3(256), 0, stream>>>(q_b, Wqb, 1024, 2, nullptr,
                                                       part, nullptr, nullptr, nullptr);
  qp_reduce<<<dim3(64), dim3(256), 0, stream>>>(part, b_q, qp);

  gemm_lds<1><<<dim3(36, 4), dim3(256), 0, stream>>>(node_b, Wobjb, 2048, 32, b_obj,
                                                     nullptr, A2b, A1b, qp);

  edge_v3<<<dim3(9, 128), dim3(512), EDGE_SMEM, stream>>>(A1b, A2b, W1f, b_l1, W2p, b_l2, pos, out);
}

// Round 6
// 140.392 us; speedup vs baseline: 2.5248x; 1.0526x over previous
//
#include <hip/hip_runtime.h>
#include <hip/hip_fp16.h>

typedef __attribute__((ext_vector_type(8))) _Float16 half8;
typedef __attribute__((ext_vector_type(2))) __fp16 fp16x2;
typedef __attribute__((ext_vector_type(4))) float f32x4;
typedef unsigned short u16;
typedef unsigned int u32;

__device__ __forceinline__ u16 f2h(float f) {
  union { _Float16 h; u16 u; } cv; cv.h = (_Float16)f; return cv.u;
}

__device__ __forceinline__ u32 pkrtz(float a, float b) {
  union { fp16x2 h; u32 u; } cv;
  cv.h = __builtin_amdgcn_cvt_pkrtz(a, b);
  return cv.u;
}

__device__ __forceinline__ f32x4 mfma16h(half8 a, half8 b, f32x4 c) {
  return __builtin_amdgcn_mfma_f32_16x16x32_f16(a, b, c, 0, 0, 0);
}

__device__ __forceinline__ void gload_lds16(const void* g, void* l) {
  __builtin_amdgcn_global_load_lds(
      (const __attribute__((address_space(1))) void*)g,
      (__attribute__((address_space(3))) void*)l, 16, 0, 0);
}

__device__ __forceinline__ half8 ldh8(const char* p) {
  union { half8 h; int4 v; } r; r.v = *(const int4*)p; return r.h;
}

// 8-wide fp16 product via v_pk_mul_f16 (4 insts for 8 elems)
__device__ __forceinline__ uint4 pkmul4(uint4 x, uint4 y) {
  union U { uint4 v; __half2 h[4]; };
  U X, Y, E; X.v = x; Y.v = y;
  #pragma unroll
  for (int i = 0; i < 4; i++) E.h[i] = __hmul2(X.h[i], Y.h[i]);
  return E.v;
}

// ---- weight-norm prep (fp16 out); rows >= Nreal zeroed ----
__global__ void wn_prep(const float* __restrict__ v, const float* __restrict__ g,
                        int K, int Nreal, u16* __restrict__ outW) {
  const int row = blockIdx.x;
  const int l = threadIdx.x;
  if (row >= Nreal) {
    for (int k = l; k < K; k += 64) outW[row * K + k] = 0;
    return;
  }
  const float* vr = v + (size_t)row * K;
  float ss = 0.f;
  for (int k = l * 4; k < K; k += 256) {
    f32x4 x = *(const f32x4*)(vr + k);
    ss += x.x * x.x + x.y * x.y + x.z * x.z + x.w * x.w;
  }
  #pragma unroll
  for (int m = 32; m >= 1; m >>= 1) ss += __shfl_xor(ss, m, 64);
  const float scale = g[row] / sqrtf(ss);
  for (int k = l; k < K; k += 64) outW[row * K + k] = f2h(vr[k] * scale);
}

// ---- W1 prep: W1f[kc(16)][row(256)][32] fp16 ----
__global__ void wn_prep_l1(const float* __restrict__ v, const float* __restrict__ g,
                           u16* __restrict__ W1f) {
  const int row = blockIdx.x;
  const int l = threadIdx.x;
  const float* vr = v + (size_t)row * 512;
  float ss = 0.f;
  for (int k = l * 4; k < 512; k += 256) {
    f32x4 x = *(const f32x4*)(vr + k);
    ss += x.x * x.x + x.y * x.y + x.z * x.z + x.w * x.w;
  }
  #pragma unroll
  for (int m = 32; m >= 1; m >>= 1) ss += __shfl_xor(ss, m, 64);
  const float scale = g[row] / sqrtf(ss);
  for (int c = l; c < 512; c += 64)
    W1f[(c >> 5) * 8192 + row * 32 + (c & 31)] = f2h(vr[c] * scale);
}

// ---- bulk fp32 -> fp16 convert ----
__global__ void cvt_f16(const float* __restrict__ in, u16* __restrict__ out, int n) {
  const int i = (blockIdx.x * 256 + threadIdx.x) * 8;
  if (i >= n) return;
  f32x4 a = *(const f32x4*)(in + i);
  f32x4 b = *(const f32x4*)(in + i + 4);
  uint4 r;
  r.x = pkrtz(a.x, a.y); r.y = pkrtz(a.z, a.w);
  r.z = pkrtz(b.x, b.y); r.w = pkrtz(b.z, b.w);
  *(uint4*)(out + i) = r;
}

// ---- pos map ----
__global__ void pos_init(int* __restrict__ pos, int n) {
  int t = blockIdx.x * 256 + threadIdx.x;
  if (t < n) pos[t] = -1;
}
__global__ void pos_scatter(const int* __restrict__ indexes, int* __restrict__ pos, int n) {
  int m = blockIdx.x * 256 + threadIdx.x;
  if (m >= n) return;
  int idx = indexes[m];
  int bi = idx / 1296;
  int rem = idx - bi * 1296;
  pos[bi * 1312 + rem] = m;
}

// ================= LDS-staged stage-1 GEMM, fp16, 128x64 tile =================
// BK=64 fp16 (128B row-chunks, same XOR-swizzle geometry as before). 4 waves
// (2M x 2N of 64x32). grid 36x8 = 288 blocks, 48KB LDS -> 3 blocks/CU.
template <int MODE>
__global__ __launch_bounds__(256, 3) void gemm_lds(
    const u16* __restrict__ Ab, const u16* __restrict__ Wb,
    int K, int nstep, const float* __restrict__ bias,
    float* __restrict__ fout, u16* __restrict__ o_a2, u16* __restrict__ o_a1,
    const float* __restrict__ qp) {
  __shared__ char smem[2][24576];   // [buf][ A 128x128B | B 64x128B ]
  const int t = threadIdx.x, l = t & 63, w = t >> 6;
  const int lr = l & 15, lg = l >> 4;
  const int wm = w & 1, wn2 = w >> 1;
  const int bm = blockIdx.x * 128, bn = blockIdx.y * 64;
  const int kbase = (MODE == 0) ? blockIdx.z * 128 : 0;
  const int ldb = K * 2;

  const char* Abase = (const char*)(Ab + (size_t)bm * K + kbase);
  const char* Bbase = (const char*)(Wb + (size_t)bn * K + kbase);

  auto stage = [&](int buf, int ks) {
    const char* asrc = Abase + ks * 128;
    const char* bsrc = Bbase + ks * 128;
    #pragma unroll
    for (int it = 0; it < 4; it++) {
      const int c = it * 256 + w * 64 + l;
      const int row = c >> 3;
      const int cb = ((c & 7) * 16) ^ ((row & 7) << 4);
      gload_lds16(asrc + (size_t)row * ldb + cb, &smem[buf][(it * 256 + w * 64) * 16]);
    }
    #pragma unroll
    for (int it = 0; it < 2; it++) {
      const int c = it * 256 + w * 64 + l;
      const int row = c >> 3;
      const int cb = ((c & 7) * 16) ^ ((row & 7) << 4);
      gload_lds16(bsrc + (size_t)row * ldb + cb,
                  &smem[buf][16384 + (it * 256 + w * 64) * 16]);
    }
  };

  stage(0, 0);
  asm volatile("s_waitcnt vmcnt(0)" ::: "memory");
  __builtin_amdgcn_s_barrier();

  f32x4 acc[4][2] = {};
  for (int ks = 0; ks < nstep; ks++) {
    const int cur = ks & 1;
    if (ks + 1 < nstep) stage(cur ^ 1, ks + 1);
    const char* As = smem[cur];
    const char* Bs = smem[cur] + 16384;
    #pragma unroll
    for (int kk = 0; kk < 2; kk++) {
      half8 af[4], bf[2];
      #pragma unroll
      for (int m = 0; m < 4; m++) {
        const int r = wm * 64 + m * 16 + lr;
        af[m] = ldh8(As + r * 128 + ((kk * 64 + lg * 16) ^ ((lr & 7) << 4)));
      }
      #pragma unroll
      for (int n = 0; n < 2; n++) {
        const int r = wn2 * 32 + n * 16 + lr;
        bf[n] = ldh8(Bs + r * 128 + ((kk * 64 + lg * 16) ^ ((lr & 7) << 4)));
      }
      #pragma unroll
      for (int m = 0; m < 4; m++)
        #pragma unroll
        for (int n = 0; n < 2; n++)
          acc[m][n] = mfma16h(af[m], bf[n], acc[m][n]);
    }
    asm volatile("s_waitcnt vmcnt(0)" ::: "memory");
    __builtin_amdgcn_s_barrier();
  }

  #pragma unroll
  for (int n = 0; n < 2; n++) {
    const int c = bn + wn2 * 32 + n * 16 + lr;
    const float bv = (MODE == 1) ? bias[c] : 0.f;
    #pragma unroll
    for (int m = 0; m < 4; m++) {
      #pragma unroll
      for (int q = 0; q < 4; q++) {
        const int r = bm + wm * 64 + m * 16 + lg * 4 + q;
        const float val = acc[m][n][q];
        if (MODE == 0) {
          fout[((size_t)blockIdx.z * 128 + r) * 512 + c] = val;
        } else {
          const float vb = val + bv;
          o_a2[(size_t)r * 512 + c] = f2h(vb);
          o_a1[(size_t)r * 512 + c] = f2h(vb * qp[(r / 36) * 512 + c]);
        }
      }
    }
  }
}

// ---- split-K reduce for qp ----
__global__ void qp_reduce(const float* __restrict__ part, const float* __restrict__ bq,
                          float* __restrict__ qp) {
  const int i = (blockIdx.x * 256 + threadIdx.x) * 4;
  f32x4 s = *(const f32x4*)(part + i);
  #pragma unroll
  for (int k = 1; k < 8; k++) {
    f32x4 v = *(const f32x4*)(part + (size_t)k * 65536 + i);
    s.x += v.x; s.y += v.y; s.z += v.z; s.w += v.w;
  }
  const int c = i & 511;
  s.x += bq[c]; s.y += bq[c + 1]; s.z += bq[c + 2]; s.w += bq[c + 3];
  *(f32x4*)(qp + i) = s;
}

// ================= fused edge kernel v4 (fp16) =================
// Block = batch bi x 144 rows. LDS: A-tables 40x1040B | Ec dbuf 2x[144][80B]
// | W1 [256][64B] = 81,024 B -> 2 blocks/CU.
// E-gen via v_pk_mul_f16 (4 insts / 8 elems); all frag reads single b128,
// bank-balanced strides (80 / 64 / 528 B).
#define OFF_EC 41600
#define OFF_W1 64640
#define EDGE_SMEM 81024

__global__ __launch_bounds__(512, 4) void edge_v4(
    const u16* __restrict__ A1g, const u16* __restrict__ A2g,
    const u16* __restrict__ W1f, const float* __restrict__ b1,
    const u16* __restrict__ W2p, const float* __restrict__ b2,
    const int* __restrict__ pos, float* __restrict__ out) {
  extern __shared__ char smem[];
  const int t = threadIdx.x, l = t & 63, w = t >> 6;
  const int lr = l & 15, lg = l >> 4;
  const int bi = blockIdx.y;
  const int mb = blockIdx.x * 144;
  const int i0 = blockIdx.x * 4;

  // ---- prologue: A1(4 rows)+A2(36 rows) fp16 @stride 1040, W1 chunk0, via global_load_lds ----
  #pragma unroll
  for (int it = 0; it < 5; it++) {
    const int row = it * 8 + w;            // 0..39, wave-uniform
    const u16* src = (row < 4) ? (A1g + (size_t)(bi * 36 + i0 + row) * 512 + l * 8)
                               : (A2g + (size_t)(bi * 36 + (row - 4)) * 512 + l * 8);
    gload_lds16(src, smem + row * 1040);
  }
  #pragma unroll
  for (int it = 0; it < 2; it++) {
    const int cb = it * 512 + w * 64;      // wave-uniform granule base
    gload_lds16(W1f + (size_t)(cb + l) * 8, smem + OFF_W1 + cb * 16);
  }
  asm volatile("s_waitcnt vmcnt(0)" ::: "memory");
  __builtin_amdgcn_s_barrier();

  // ---- E-gen granules: 576 x 16B (8 elems); g0 = t, g1 = 512+t (t<64) ----
  const int r0 = t >> 2, sc = (t & 3) * 16;
  const int ii0 = r0 / 36, jj0 = r0 - ii0 * 36;
  const char* x0p = smem + ii0 * 1040 + sc;
  const char* y0p = smem + 4160 + jj0 * 1040 + sc;
  char* e0p = smem + OFF_EC + r0 * 80 + sc;
  const int r1 = 128 + (t >> 2);
  const int jj1 = r1 - 108;                // ii1 == 3
  const char* x1p = smem + 3 * 1040 + sc;
  const char* y1p = smem + 4160 + jj1 * 1040 + sc;
  char* e1p = smem + OFF_EC + r1 * 80 + sc;

  auto egen = [&](int kc, int buf) {
    const int kb = kc * 64;                // 32 fp16 per kc
    const int bo = buf * 11520;
    {
      uint4 x = *(const uint4*)(x0p + kb);
      uint4 y = *(const uint4*)(y0p + kb);
      *(uint4*)(e0p + bo) = pkmul4(x, y);
    }
    if (t < 64) {
      uint4 x = *(const uint4*)(x1p + kb);
      uint4 y = *(const uint4*)(y1p + kb);
      *(uint4*)(e1p + bo) = pkmul4(x, y);
    }
  };

  egen(0, 0);
  __syncthreads();

  const float b1v0 = b1[w * 32 + lr];
  const float b1v1 = b1[w * 32 + 16 + lr];

  f32x4 acc[9][2] = {};
  int cur = 0;

  for (int kc = 0; kc < 16; kc++) {
    const bool more = (kc < 15);
    int4 s0, s1;
    if (more) {                            // T14: W1(kc+1) global->reg early
      const u16* wsrc = W1f + (size_t)(kc + 1) * 8192;
      s0 = *(const int4*)(wsrc + t * 8);
      s1 = *(const int4*)(wsrc + (t + 512) * 8);
    }
    if (more) egen(kc + 1, cur ^ 1);

    {
      const char* w1b = smem + OFF_W1;
      const char* ecb = smem + OFF_EC + cur * 11520;
      half8 bf0 = ldh8(w1b + (w * 32 + lr) * 64 + lg * 16);
      half8 bf1 = ldh8(w1b + (w * 32 + 16 + lr) * 64 + lg * 16);
      #pragma unroll
      for (int m = 0; m < 9; m++) {
        half8 af = ldh8(ecb + (m * 16 + lr) * 80 + lg * 16);
        acc[m][0] = mfma16h(af, bf0, acc[m][0]);
        acc[m][1] = mfma16h(af, bf1, acc[m][1]);
      }
    }
    __syncthreads();                       // W1 + Ec[cur] reads done
    if (more) {
      *(int4*)(smem + OFF_W1 + t * 16) = s0;
      *(int4*)(smem + OFF_W1 + (t + 512) * 16) = s1;
    }
    __syncthreads();                       // W1(kc+1) ready
    cur ^= 1;
  }

  // ---- epilogue: bias+relu -> fp16 h tile [144][528B] (aliases A/Ec/W1) ----
  #pragma unroll
  for (int m = 0; m < 9; m++) {
    #pragma unroll
    for (int n = 0; n < 2; n++) {
      const int c = w * 32 + n * 16 + lr;
      const float bv = (n == 0) ? b1v0 : b1v1;
      #pragma unroll
      for (int qq = 0; qq < 2; qq++) {
        const float v0 = fmaxf(acc[m][n][2 * qq] + bv, 0.f);
        const float v1 = fmaxf(acc[m][n][2 * qq + 1] + bv, 0.f);
        const u32 p = pkrtz(v0, v1);
        const int r = m * 16 + lg * 4 + 2 * qq;
        *(u16*)(smem + r * 528 + c * 2) = (u16)p;
        *(u16*)(smem + (r + 1) * 528 + c * 2) = (u16)(p >> 16);
      }
    }
  }
  __syncthreads();

  // ---- GEMM2: out = h @ W2p^T + b2, K=256 fp16 ----
  half8 w2f[8];
  #pragma unroll
  for (int kk = 0; kk < 8; kk++)
    w2f[kk] = ldh8((const char*)W2p + lr * 512 + kk * 64 + lg * 16);

  #pragma unroll
  for (int tt = 0; tt < 2; tt++) {
    const int tile = tt * 8 + w;
    if (tile < 9) {
      f32x4 a2c = {0.f, 0.f, 0.f, 0.f};
      #pragma unroll
      for (int kk = 0; kk < 8; kk++) {
        half8 af = ldh8(smem + (tile * 16 + lr) * 528 + kk * 64 + lg * 16);
        a2c = mfma16h(af, w2f[kk], a2c);
      }
      if (lr < 8) {
        const float b2v = b2[lr];
        #pragma unroll
        for (int q = 0; q < 4; q++) {
          const int rl = tile * 16 + lg * 4 + q;
          const int m = pos[bi * 1312 + mb + rl];
          if (m >= 0) out[(size_t)m * 8 + lr] = a2c[q] + b2v;
        }
      }
    }
  }
}

extern "C" void kernel_launch(void* const* d_in, const int* in_sizes, int n_in,
                              void* d_out, int out_size, void* d_ws, size_t ws_size,
                              hipStream_t stream) {
  const float* node_feats = (const float*)d_in[0];
  const float* q_feats    = (const float*)d_in[1];
  const int*   indexes    = (const int*)d_in[2];
  const float* v_obj = (const float*)d_in[3];
  const float* g_obj = (const float*)d_in[4];
  const float* b_obj = (const float*)d_in[5];
  const float* v_q   = (const float*)d_in[6];
  const float* g_q   = (const float*)d_in[7];
  const float* b_q   = (const float*)d_in[8];
  const float* v_l1  = (const float*)d_in[9];
  const float* g_l1  = (const float*)d_in[10];
  const float* b_l1  = (const float*)d_in[11];
  const float* v_l2  = (const float*)d_in[12];
  const float* g_l2  = (const float*)d_in[13];
  const float* b_l2  = (const float*)d_in[14];
  float* out = (float*)d_out;

  char* ws = (char*)d_ws;
  u16*   node_h = (u16*)(ws + 0);               // 18,874,368
  u16*   q_h    = (u16*)(ws + 18874368);        //    262,144
  u16*   Wobjh  = (u16*)(ws + 19136512);        //  2,097,152
  u16*   Wqh    = (u16*)(ws + 21233664);        //  1,048,576
  u16*   W1f    = (u16*)(ws + 22282240);        //    262,144 (16x256x32 fp16)
  u16*   W2p    = (u16*)(ws + 22544384);        //      8,192
  float* qp     = (float*)(ws + 22552576);      //    262,144
  u16*   A1h    = (u16*)(ws + 22814720);        //  4,718,592
  u16*   A2h    = (u16*)(ws + 27533312);        //  4,718,592
  int*   pos    = (int*)(ws + 32251904);        //    671,744
  float* part   = (float*)(ws + 32923648);      //  2,097,152

  wn_prep<<<dim3(512), dim3(64), 0, stream>>>(v_obj, g_obj, 2048, 512, Wobjh);
  wn_prep<<<dim3(512), dim3(64), 0, stream>>>(v_q,   g_q,   1024, 512, Wqh);
  wn_prep_l1<<<dim3(256), dim3(64), 0, stream>>>(v_l1, g_l1, W1f);
  wn_prep<<<dim3(16),  dim3(64), 0, stream>>>(v_l2,  g_l2,  256,  8,   W2p);

  cvt_f16<<<dim3(4608), dim3(256), 0, stream>>>(node_feats, node_h, 9437184);
  cvt_f16<<<dim3(64),   dim3(256), 0, stream>>>(q_feats,    q_h,    131072);

  pos_init<<<dim3(656), dim3(256), 0, stream>>>(pos, 128 * 1312);
  pos_scatter<<<dim3(630), dim3(256), 0, stream>>>(indexes, pos, 161280);

  gemm_lds<0><<<dim3(1, 8, 8), dim3(256), 0, stream>>>(q_h, Wqh, 1024, 2, nullptr,
                                                       part, nullptr, nullptr, nullptr);
  qp_reduce<<<dim3(64), dim3(256), 0, stream>>>(part, b_q, qp);

  gemm_lds<1><<<dim3(36, 8), dim3(256), 0, stream>>>(node_h, Wobjh, 2048, 32, b_obj,
                                                     nullptr, A2h, A1h, qp);

  edge_v4<<<dim3(9, 128), dim3(512), EDGE_SMEM, stream>>>(A1h, A2h, W1f, b_l1, W2p, b_l2, pos, out);
}